// Round 6
// baseline (165.627 us; speedup 1.0000x reference)
//
#include <hip/hip_runtime.h>
#include <hip/hip_bf16.h>

#define B_  8
#define C_  32
#define H_  128
#define W_  128
#define CO_ 64
#define KK_ 9
#define HW_ (H_*W_)
#define TP_ 128          // pixels per block
#define NT_ 128          // threads per block (2 waves)

typedef short s16x8 __attribute__((ext_vector_type(8)));   // 8 bf16 operand
typedef float f32x4 __attribute__((ext_vector_type(4)));   // MFMA accumulator

__device__ __forceinline__ short bf16b(float f) {
    __hip_bfloat16 h = __float2bfloat16(f);
    return __builtin_bit_cast(short, h);
}

// R5 structure: per-pixel offset conv kept in REGISTERS (kk fully unrolled ->
// all oacc indices static), per-kk GEMM OUT[64x128] += W9[64x32]*S[32x128] on
// MFMA, double-buffered Sl/Wl with ONE barrier per kk, gather(kk+1) issued
// before MFMA(kk). blockIdx&7 = image -> each XCD's L2 holds one 2.1MB image.
__global__ __launch_bounds__(NT_, 2) void dconv_fused(
    const float* __restrict__ x,
    const float* __restrict__ w_off,
    const float* __restrict__ b_off,
    const float* __restrict__ w_mod,
    const float* __restrict__ b_mod,
    const float* __restrict__ w_reg,
    float* __restrict__ out)
{
    __shared__ short Sl[2][4][TP_][8];   // bf16 samples [buf][kg][pix][j] 16KB
    __shared__ short Wl[2][4][CO_][8];   // bf16 weights [buf][kg][o][j]    8KB

    const int tid  = threadIdx.x;
    const int bidx = blockIdx.x & 7;     // image == XCD (hw: XCD = blk % 8)
    const int hwbase = (blockIdx.x >> 3) * TP_;
    const int hw = hwbase + tid;
    const int h  = hw / W_;
    const int w  = hw % W_;
    const float* xb = x + bidx * (C_ * HW_);

    // ---------- stage 1: 3x3 conv -> 18 clamped offsets + 9 masks (regs) ---
    float oacc[27];
    #pragma unroll
    for (int j = 0; j < 18; ++j) oacc[j] = b_off[j];
    #pragma unroll
    for (int j = 0; j < 9; ++j)  oacc[18 + j] = b_mod[j];

    for (int c = 0; c < C_; ++c) {
        float xv[9];
        #pragma unroll
        for (int t = 0; t < 9; ++t) {
            const int yy = h + t / 3 - 1;
            const int xx = w + t % 3 - 1;
            const bool ok = (yy >= 0) & (yy < H_) & (xx >= 0) & (xx < W_);
            xv[t] = ok ? xb[c * HW_ + yy * W_ + xx] : 0.0f;
        }
        const float* wo = w_off + c * 9;
        #pragma unroll
        for (int j = 0; j < 18; ++j) {
            #pragma unroll
            for (int t = 0; t < 9; ++t)
                oacc[j] = fmaf(wo[j * (C_ * 9) + t], xv[t], oacc[j]);
        }
        const float* wm = w_mod + c * 9;
        #pragma unroll
        for (int j = 0; j < 9; ++j) {
            #pragma unroll
            for (int t = 0; t < 9; ++t)
                oacc[18 + j] = fmaf(wm[j * (C_ * 9) + t], xv[t], oacc[18 + j]);
        }
    }
    #pragma unroll
    for (int j = 0; j < 18; ++j)
        oacc[j] = fminf(fmaxf(oacc[j], -32.0f), 32.0f);
    #pragma unroll
    for (int j = 0; j < 9; ++j)
        oacc[18 + j] = 2.0f / (1.0f + expf(-oacc[18 + j]));

    // ---------- helpers (kk2 is compile-time constant at every call) -------
    auto GATHER = [&](int kk2, float* sarr) {
        const int ky = kk2 / 3, kx = kk2 % 3;
        const float py = oacc[kk2 * 2 + 0] + (float)(h - 1 + ky);
        const float px = oacc[kk2 * 2 + 1] + (float)(w - 1 + kx);
        const float m  = oacc[18 + kk2];
        const float y0f = floorf(py), x0f = floorf(px);
        const float dy = py - y0f,   dx = px - x0f;
        const int y0 = (int)y0f, x0 = (int)x0f;
        const int y1 = y0 + 1,   x1 = x0 + 1;
        const bool vy0 = (y0 >= 0) & (y0 < H_);
        const bool vy1 = (y1 >= 0) & (y1 < H_);
        const bool vx0 = (x0 >= 0) & (x0 < W_);
        const bool vx1 = (x1 >= 0) & (x1 < W_);
        const float wm00 = (vy0 & vx0) ? (1.0f - dy) * (1.0f - dx) * m : 0.0f;
        const float wm01 = (vy0 & vx1) ? (1.0f - dy) * dx * m         : 0.0f;
        const float wm10 = (vy1 & vx0) ? dy * (1.0f - dx) * m         : 0.0f;
        const float wm11 = (vy1 & vx1) ? dy * dx * m                  : 0.0f;
        const int y0c = min(max(y0, 0), H_ - 1), y1c = min(max(y1, 0), H_ - 1);
        const int x0c = min(max(x0, 0), W_ - 1), x1c = min(max(x1, 0), W_ - 1);
        const int i00 = y0c * W_ + x0c, i01 = y0c * W_ + x1c;
        const int i10 = y1c * W_ + x0c, i11 = y1c * W_ + x1c;
        #pragma unroll
        for (int c4 = 0; c4 < C_; c4 += 4) {
            #pragma unroll
            for (int u = 0; u < 4; ++u) {
                const float* xc = xb + (c4 + u) * HW_;
                sarr[c4 + u] = wm00 * xc[i00] + wm01 * xc[i01]
                             + wm10 * xc[i10] + wm11 * xc[i11];
            }
        }
    };
    auto WSTAGE = [&](int kk2, s16x8* wv) {       // 2 vectors per thread
        #pragma unroll
        for (int i = 0; i < 2; ++i) {
            const int v = i * NT_ + tid;          // 0..255 -> (kg,o)
            const int kg = v >> 6, o = v & 63;
            s16x8 t;
            #pragma unroll
            for (int j = 0; j < 8; ++j)
                t[j] = bf16b(w_reg[(o * C_ + kg * 8 + j) * 9 + kk2]);
            wv[i] = t;
        }
    };
    auto PACK = [&](int buf, const float* sarr, const s16x8* wv) {
        #pragma unroll
        for (int kg = 0; kg < 4; ++kg) {
            s16x8 v;
            #pragma unroll
            for (int j = 0; j < 8; ++j) v[j] = bf16b(sarr[kg * 8 + j]);
            *(s16x8*)&Sl[buf][kg][tid][0] = v;
        }
        #pragma unroll
        for (int i = 0; i < 2; ++i) {
            const int v = i * NT_ + tid;
            const int kg = v >> 6, o = v & 63;
            *(s16x8*)&Wl[buf][kg][o][0] = wv[i];
        }
    };

    // ---------- prologue: fill buffer 0 ------------------------------------
    {
        float s0[C_];
        s16x8 wv0[2];
        GATHER(0, s0);
        WSTAGE(0, wv0);
        PACK(0, s0, wv0);
    }
    __syncthreads();

    const int lane = tid & 63;
    const int wid  = tid >> 6;       // 2 waves: pixel halves
    const int fr   = lane & 15;
    const int fq   = lane >> 4;

    f32x4 acc[4][4];                 // [o-tile][p-tile]
    #pragma unroll
    for (int ot = 0; ot < 4; ++ot)
        #pragma unroll
        for (int pt = 0; pt < 4; ++pt)
            acc[ot][pt] = (f32x4){0.f, 0.f, 0.f, 0.f};

    #pragma unroll
    for (int kk = 0; kk < KK_; ++kk) {
        const int cur = kk & 1, nxt = cur ^ 1;

        s16x8 af[4], bfg[4];
        #pragma unroll
        for (int ot = 0; ot < 4; ++ot)
            af[ot] = *(const s16x8*)&Wl[cur][fq][ot * 16 + fr][0];
        #pragma unroll
        for (int pt = 0; pt < 4; ++pt)
            bfg[pt] = *(const s16x8*)&Sl[cur][fq][wid * 64 + pt * 16 + fr][0];

        float sn[C_];
        s16x8 wvn[2];
        if (kk + 1 < KK_) {          // issue next tile's loads under MFMA
            GATHER(kk + 1, sn);
            WSTAGE(kk + 1, wvn);
        }

        #pragma unroll
        for (int ot = 0; ot < 4; ++ot)
            #pragma unroll
            for (int pt = 0; pt < 4; ++pt)
                acc[ot][pt] = __builtin_amdgcn_mfma_f32_16x16x32_bf16(
                                  af[ot], bfg[pt], acc[ot][pt], 0, 0, 0);

        if (kk + 1 < KK_) {
            PACK(nxt, sn, wvn);
            __syncthreads();         // writes visible; reads of cur all done
        }
    }

    // ---------- epilogue: D lane l -> o = ot*16+fq*4+j, pix = wid*64+pt*16+fr
    float* outb = out + (size_t)bidx * (CO_ * HW_) + hwbase;
    #pragma unroll
    for (int ot = 0; ot < 4; ++ot) {
        #pragma unroll
        for (int j = 0; j < 4; ++j) {
            const int o = ot * 16 + fq * 4 + j;
            float* row = outb + o * HW_ + wid * 64 + fr;
            #pragma unroll
            for (int pt = 0; pt < 4; ++pt)
                row[pt * 16] = acc[ot][pt][j];
        }
    }
}

extern "C" void kernel_launch(void* const* d_in, const int* in_sizes, int n_in,
                              void* d_out, int out_size, void* d_ws, size_t ws_size,
                              hipStream_t stream) {
    const float* x     = (const float*)d_in[0];
    const float* w_off = (const float*)d_in[1];
    const float* b_off = (const float*)d_in[2];
    const float* w_mod = (const float*)d_in[3];
    const float* b_mod = (const float*)d_in[4];
    const float* w_reg = (const float*)d_in[5];
    float* out = (float*)d_out;
    (void)d_ws; (void)ws_size;

    dconv_fused<<<B_ * HW_ / TP_, NT_, 0, stream>>>(x, w_off, b_off, w_mod,
                                                    b_mod, w_reg, out);
}